// Round 4
// baseline (155.897 us; speedup 1.0000x reference)
//
#include <hip/hip_runtime.h>
#include <math.h>

#define B_ 4
#define L_ 4096
#define D_ 128
#define N_ 16
#define DT_ 0.1f
#define CHUNK_ 32
#define NC_ 128   // L_/CHUNK_

// ws layout in floats:
#define ABAR_OFF 0                        // abar [B][L][N]
#define COEF_OFF (ABAR_OFF + 262144)      // coef [B][L][N]
#define CC_OFF   (COEF_OFF + 262144)      // Cc   [B][L][N]
#define HL_OFF   (CC_OFF + 262144)        // hL [B][NC][D][N]
#define P_OFF    (HL_OFF + 1048576)       // P  [B][NC][N]
// total = P_OFF + 8192 floats ~= 7.4 MB

// K1 v2: fused projections + discretization. 512 blocks x 256 threads.
// tile = bid>>1 (64 rows), type = bid&1: type0 -> Bp+delta -> abar/coef;
// type1 -> Cc. 4 waves/block, wave w owns 4 output cols, full K=128/lane,
// W via wave-uniform scalar loads directly from Wb/Wc/Wd (already [col][k]).
__global__ __launch_bounds__(256) void k1_proj(const float* __restrict__ x,
                                               const float* __restrict__ A,
                                               const float* __restrict__ Wb,
                                               const float* __restrict__ bb,
                                               const float* __restrict__ Wc,
                                               const float* __restrict__ bc,
                                               const float* __restrict__ Wd,
                                               const float* __restrict__ bd,
                                               float* __restrict__ ws) {
    __shared__ float xs[64][129];
    __shared__ float proj[64][18];

    float* abar_o = ws + ABAR_OFF;
    float* coef_o = ws + COEF_OFF;
    float* cc_o   = ws + CC_OFF;

    const int t = threadIdx.x;
    const int bt = blockIdx.x & 1;
    const size_t row0 = (size_t)(blockIdx.x >> 1) * 64;

    // stage x tile (64 rows x 128) coalesced
    const float4* xg = (const float4*)(x + row0 * 128);
    for (int i = t; i < 2048; i += 256) {
        float4 v = xg[i];
        int r = i >> 5;
        int c0 = (i & 31) << 2;
        xs[r][c0]     = v.x;
        xs[r][c0 + 1] = v.y;
        xs[r][c0 + 2] = v.z;
        xs[r][c0 + 3] = v.w;
    }
    __syncthreads();

    const int w = __builtin_amdgcn_readfirstlane(t >> 6);  // 0..3, wave-uniform
    const int lane = t & 63;

    const float* cbase = (bt == 0 ? Wb : Wc) + (size_t)w * 4 * 128;
    float a0 = 0.f, a1 = 0.f, a2 = 0.f, a3 = 0.f;
#pragma unroll 8
    for (int k = 0; k < 128; ++k) {
        float xv = xs[lane][k];
        a0 = fmaf(xv, cbase[k],       a0);
        a1 = fmaf(xv, cbase[128 + k], a1);
        a2 = fmaf(xv, cbase[256 + k], a2);
        a3 = fmaf(xv, cbase[384 + k], a3);
    }
    proj[lane][w * 4]     = a0;
    proj[lane][w * 4 + 1] = a1;
    proj[lane][w * 4 + 2] = a2;
    proj[lane][w * 4 + 3] = a3;
    if (bt == 0 && w == 3) {
        float ad = 0.f;
#pragma unroll 8
        for (int k = 0; k < 128; ++k) ad = fmaf(xs[lane][k], Wd[k], ad);
        proj[lane][16] = ad;
    }
    __syncthreads();

    // epilogue: thread (r = t&63, g = t>>6) handles n = 4g..4g+3
    const int r = t & 63;
    const int g = t >> 6;
    const int n0 = g * 4;
    const size_t orow = (row0 + (size_t)r) * 16 + n0;

    if (bt == 0) {
        float zd = proj[r][16] + bd[0];
        float sp = fmaxf(zd, 0.f) + log1pf(expf(-fabsf(zd)));  // stable softplus
        float delta = sp + DT_;
        float4 ab4, cf4;
        {
            float Bp = proj[r][n0] + bb[n0];
            float dA = delta * A[n0];
            ab4.x = expf(dA);
            cf4.x = (1.f - expf(-dA)) * delta * Bp;
        }
        {
            float Bp = proj[r][n0 + 1] + bb[n0 + 1];
            float dA = delta * A[n0 + 1];
            ab4.y = expf(dA);
            cf4.y = (1.f - expf(-dA)) * delta * Bp;
        }
        {
            float Bp = proj[r][n0 + 2] + bb[n0 + 2];
            float dA = delta * A[n0 + 2];
            ab4.z = expf(dA);
            cf4.z = (1.f - expf(-dA)) * delta * Bp;
        }
        {
            float Bp = proj[r][n0 + 3] + bb[n0 + 3];
            float dA = delta * A[n0 + 3];
            ab4.w = expf(dA);
            cf4.w = (1.f - expf(-dA)) * delta * Bp;
        }
        *(float4*)(abar_o + orow) = ab4;
        *(float4*)(coef_o + orow) = cf4;
    } else {
        float4 cv4;
        cv4.x = proj[r][n0]     + bc[n0];
        cv4.y = proj[r][n0 + 1] + bc[n0 + 1];
        cv4.z = proj[r][n0 + 2] + bc[n0 + 2];
        cv4.w = proj[r][n0 + 3] + bc[n0 + 3];
        *(float4*)(cc_o + orow) = cv4;
    }
}

// K2a: per-chunk local scan (h0=0) -> hL[b][c][d][n], P[b][c][n].
// 4096 waves: gw = [b:2][dgrp:3][c:7]; lane = ng*16+dq; d = dgrp*16+dq; n = ng*4+j.
__global__ __launch_bounds__(256) void k2a_chunk(const float* __restrict__ x,
                                                 float* __restrict__ ws) {
    const float* abar = ws + ABAR_OFF;
    const float* coef = ws + COEF_OFF;
    float* hL = ws + HL_OFF;
    float* Pp = ws + P_OFF;

    const int gw = blockIdx.x * 4 + (threadIdx.x >> 6);
    const int lane = threadIdx.x & 63;
    const int b = gw >> 10;
    const int dgrp = (gw >> 7) & 7;
    const int c = gw & 127;
    const int ng = lane >> 4;
    const int dq = lane & 15;
    const int d = dgrp * 16 + dq;
    const int l0 = c * CHUNK_;
    const size_t sbase = ((size_t)b * L_ + l0) * 16 + ng * 4;
    const float* px = x + ((size_t)b * L_ + l0) * 128 + d;

    float h0v = 0.f, h1v = 0.f, h2v = 0.f, h3v = 0.f;
    float P0 = 1.f, P1 = 1.f, P2 = 1.f, P3 = 1.f;
#pragma unroll 8
    for (int t = 0; t < CHUNK_; ++t) {
        float4 a4 = *(const float4*)(abar + sbase + t * 16);
        float4 c4 = *(const float4*)(coef + sbase + t * 16);
        float xv = px[t * 128];
        h0v = fmaf(a4.x, h0v, c4.x * xv);
        h1v = fmaf(a4.y, h1v, c4.y * xv);
        h2v = fmaf(a4.z, h2v, c4.z * xv);
        h3v = fmaf(a4.w, h3v, c4.w * xv);
        P0 *= a4.x; P1 *= a4.y; P2 *= a4.z; P3 *= a4.w;
    }
    *(float4*)(hL + (((size_t)(b * NC_ + c)) * 128 + d) * 16 + ng * 4) =
        make_float4(h0v, h1v, h2v, h3v);
    if (dq == 0) {
        *(float4*)(Pp + ((size_t)(b * NC_ + c)) * 16 + ng * 4) =
            make_float4(P0, P1, P2, P3);
    }
}

// K2bc: per-block combine (h0 from preceding chunks' hL/P) + rescan + y.
// Same geometry as k2a. No LDS.
__global__ __launch_bounds__(256) void k2c_scan(const float* __restrict__ x,
                                                const float* __restrict__ ws,
                                                float* __restrict__ y) {
    const float* abar = ws + ABAR_OFF;
    const float* coef = ws + COEF_OFF;
    const float* cc   = ws + CC_OFF;
    const float* hL   = ws + HL_OFF;
    const float* Pp   = ws + P_OFF;

    const int gw = blockIdx.x * 4 + (threadIdx.x >> 6);
    const int lane = threadIdx.x & 63;
    const int b = gw >> 10;
    const int dgrp = (gw >> 7) & 7;
    const int c = gw & 127;
    const int ng = lane >> 4;
    const int dq = lane & 15;
    const int d = dgrp * 16 + dq;
    const int l0 = c * CHUNK_;
    const size_t sbase = ((size_t)b * L_ + l0) * 16 + ng * 4;
    const float* px = x + ((size_t)b * L_ + l0) * 128 + d;
    float* py = y + ((size_t)b * L_ + l0) * 128 + d;

    // combine: h0 = state after chunks 0..c-1
    float h0v = 0.f, h1v = 0.f, h2v = 0.f, h3v = 0.f;
    const float* hLp = hL + ((size_t)b * NC_) * 2048 + d * 16 + ng * 4;
    const float* Pq  = Pp + ((size_t)b * NC_) * 16 + ng * 4;
#pragma unroll 4
    for (int cc2 = 0; cc2 < c; ++cc2) {
        float4 hl4 = *(const float4*)(hLp + (size_t)cc2 * 2048);
        float4 p4  = *(const float4*)(Pq + (size_t)cc2 * 16);
        h0v = fmaf(p4.x, h0v, hl4.x);
        h1v = fmaf(p4.y, h1v, hl4.y);
        h2v = fmaf(p4.z, h2v, hl4.z);
        h3v = fmaf(p4.w, h3v, hl4.w);
    }

    // rescan with y output
#pragma unroll 4
    for (int t = 0; t < CHUNK_; ++t) {
        float4 a4 = *(const float4*)(abar + sbase + t * 16);
        float4 c4 = *(const float4*)(coef + sbase + t * 16);
        float4 C4 = *(const float4*)(cc   + sbase + t * 16);
        float xv = px[t * 128];
        h0v = fmaf(a4.x, h0v, c4.x * xv);
        h1v = fmaf(a4.y, h1v, c4.y * xv);
        h2v = fmaf(a4.z, h2v, c4.z * xv);
        h3v = fmaf(a4.w, h3v, c4.w * xv);
        float yv = h0v * C4.x + h1v * C4.y + h2v * C4.z + h3v * C4.w;
        yv += __shfl_xor(yv, 16);
        yv += __shfl_xor(yv, 32);
        if (ng == 0) py[t * 128] = yv;
    }
}

extern "C" void kernel_launch(void* const* d_in, const int* in_sizes, int n_in,
                              void* d_out, int out_size, void* d_ws, size_t ws_size,
                              hipStream_t stream) {
    const float* x  = (const float*)d_in[0];
    const float* A  = (const float*)d_in[1];
    const float* Wb = (const float*)d_in[2];
    const float* bb = (const float*)d_in[3];
    const float* Wc = (const float*)d_in[4];
    const float* bc = (const float*)d_in[5];
    const float* Wd = (const float*)d_in[6];
    const float* bd = (const float*)d_in[7];
    float* ws = (float*)d_ws;
    float* y  = (float*)d_out;

    k1_proj<<<512, 256, 0, stream>>>(x, A, Wb, bb, Wc, bc, Wd, bd, ws);
    k2a_chunk<<<1024, 256, 0, stream>>>(x, ws);
    k2c_scan<<<1024, 256, 0, stream>>>(x, ws, y);
}

// Round 5
// 145.722 us; speedup vs baseline: 1.0698x; 1.0698x over previous
//
#include <hip/hip_runtime.h>
#include <math.h>

#define B_ 4
#define L_ 4096
#define D_ 128
#define N_ 16
#define DT_ 0.1f
#define CHUNK_ 32
#define NC_ 128   // L_/CHUNK_

// ws layout in floats:
#define ABAR_OFF 0                        // abar [B][L][N]
#define COEF_OFF (ABAR_OFF + 262144)      // coef [B][L][N]
#define CC_OFF   (COEF_OFF + 262144)      // Cc   [B][L][N]
#define HL_OFF   (CC_OFF + 262144)        // hL [B][NC][D][N]
#define H0_OFF   (HL_OFF + 1048576)       // h0 [B][NC][D][N]
#define P_OFF    (H0_OFF + 1048576)       // P  [B][NC][N]

// K1: fused projections + discretization. 512 blocks x 256 threads.
// tile = bid>>1 (64 rows), type = bid&1: type0 -> Bp+delta -> abar/coef; type1 -> Cc.
__global__ __launch_bounds__(256) void k1_proj(const float* __restrict__ x,
                                               const float* __restrict__ A,
                                               const float* __restrict__ Wb,
                                               const float* __restrict__ bb,
                                               const float* __restrict__ Wc,
                                               const float* __restrict__ bc,
                                               const float* __restrict__ Wd,
                                               const float* __restrict__ bd,
                                               float* __restrict__ ws) {
    __shared__ float xs[64][129];
    __shared__ float proj[64][18];

    float* abar_o = ws + ABAR_OFF;
    float* coef_o = ws + COEF_OFF;
    float* cc_o   = ws + CC_OFF;

    const int t = threadIdx.x;
    const int bt = blockIdx.x & 1;
    const size_t row0 = (size_t)(blockIdx.x >> 1) * 64;

    const float4* xg = (const float4*)(x + row0 * 128);
    for (int i = t; i < 2048; i += 256) {
        float4 v = xg[i];
        int r = i >> 5;
        int c0 = (i & 31) << 2;
        xs[r][c0]     = v.x;
        xs[r][c0 + 1] = v.y;
        xs[r][c0 + 2] = v.z;
        xs[r][c0 + 3] = v.w;
    }
    __syncthreads();

    const int w = __builtin_amdgcn_readfirstlane(t >> 6);
    const int lane = t & 63;

    const float* cbase = (bt == 0 ? Wb : Wc) + (size_t)w * 4 * 128;
    float a0 = 0.f, a1 = 0.f, a2 = 0.f, a3 = 0.f;
#pragma unroll 8
    for (int k = 0; k < 128; ++k) {
        float xv = xs[lane][k];
        a0 = fmaf(xv, cbase[k],       a0);
        a1 = fmaf(xv, cbase[128 + k], a1);
        a2 = fmaf(xv, cbase[256 + k], a2);
        a3 = fmaf(xv, cbase[384 + k], a3);
    }
    proj[lane][w * 4]     = a0;
    proj[lane][w * 4 + 1] = a1;
    proj[lane][w * 4 + 2] = a2;
    proj[lane][w * 4 + 3] = a3;
    if (bt == 0 && w == 3) {
        float ad = 0.f;
#pragma unroll 8
        for (int k = 0; k < 128; ++k) ad = fmaf(xs[lane][k], Wd[k], ad);
        proj[lane][16] = ad;
    }
    __syncthreads();

    const int r = t & 63;
    const int g = t >> 6;
    const int n0 = g * 4;
    const size_t orow = (row0 + (size_t)r) * 16 + n0;

    if (bt == 0) {
        float zd = proj[r][16] + bd[0];
        float sp = fmaxf(zd, 0.f) + log1pf(expf(-fabsf(zd)));  // stable softplus
        float delta = sp + DT_;
        float4 ab4, cf4;
        { float Bp = proj[r][n0]     + bb[n0];     float dA = delta * A[n0];
          ab4.x = expf(dA); cf4.x = (1.f - expf(-dA)) * delta * Bp; }
        { float Bp = proj[r][n0 + 1] + bb[n0 + 1]; float dA = delta * A[n0 + 1];
          ab4.y = expf(dA); cf4.y = (1.f - expf(-dA)) * delta * Bp; }
        { float Bp = proj[r][n0 + 2] + bb[n0 + 2]; float dA = delta * A[n0 + 2];
          ab4.z = expf(dA); cf4.z = (1.f - expf(-dA)) * delta * Bp; }
        { float Bp = proj[r][n0 + 3] + bb[n0 + 3]; float dA = delta * A[n0 + 3];
          ab4.w = expf(dA); cf4.w = (1.f - expf(-dA)) * delta * Bp; }
        *(float4*)(abar_o + orow) = ab4;
        *(float4*)(coef_o + orow) = cf4;
    } else {
        float4 cv4;
        cv4.x = proj[r][n0]     + bc[n0];
        cv4.y = proj[r][n0 + 1] + bc[n0 + 1];
        cv4.z = proj[r][n0 + 2] + bc[n0 + 2];
        cv4.w = proj[r][n0 + 3] + bc[n0 + 3];
        *(float4*)(cc_o + orow) = cv4;
    }
}

// K2a: per-chunk local scan (h0=0) -> hL, P. Manual 2-stage prefetch for ILP.
// gw = [b:2][dgrp:3][c:7]; lane = ng*16+dq; d = dgrp*16+dq.
__global__ __launch_bounds__(256, 4) void k2a_chunk(const float* __restrict__ x,
                                                    float* __restrict__ ws) {
    const float* abar = ws + ABAR_OFF;
    const float* coef = ws + COEF_OFF;
    float* hL = ws + HL_OFF;
    float* Pp = ws + P_OFF;

    const int gw = blockIdx.x * 4 + (threadIdx.x >> 6);
    const int lane = threadIdx.x & 63;
    const int b = gw >> 10;
    const int dgrp = (gw >> 7) & 7;
    const int c = gw & 127;
    const int ng = lane >> 4;
    const int dq = lane & 15;
    const int d = dgrp * 16 + dq;
    const int l0 = c * CHUNK_;
    const float* pa = abar + ((size_t)b * L_ + l0) * 16 + ng * 4;
    const float* pc = coef + ((size_t)b * L_ + l0) * 16 + ng * 4;
    const float* px = x + ((size_t)b * L_ + l0) * 128 + d;

    float h0v = 0.f, h1v = 0.f, h2v = 0.f, h3v = 0.f;
    float P0 = 1.f, P1 = 1.f, P2 = 1.f, P3 = 1.f;

    float4 a4 = *(const float4*)pa;
    float4 c4 = *(const float4*)pc;
    float xv = px[0];
#pragma unroll 8
    for (int t = 0; t < CHUNK_ - 1; ++t) {
        float4 an = *(const float4*)(pa + (t + 1) * 16);
        float4 cn = *(const float4*)(pc + (t + 1) * 16);
        float xn = px[(t + 1) * 128];
        h0v = fmaf(a4.x, h0v, c4.x * xv);
        h1v = fmaf(a4.y, h1v, c4.y * xv);
        h2v = fmaf(a4.z, h2v, c4.z * xv);
        h3v = fmaf(a4.w, h3v, c4.w * xv);
        P0 *= a4.x; P1 *= a4.y; P2 *= a4.z; P3 *= a4.w;
        a4 = an; c4 = cn; xv = xn;
    }
    h0v = fmaf(a4.x, h0v, c4.x * xv);
    h1v = fmaf(a4.y, h1v, c4.y * xv);
    h2v = fmaf(a4.z, h2v, c4.z * xv);
    h3v = fmaf(a4.w, h3v, c4.w * xv);
    P0 *= a4.x; P1 *= a4.y; P2 *= a4.z; P3 *= a4.w;

    *(float4*)(hL + (((size_t)(b * NC_ + c)) * 128 + d) * 16 + ng * 4) =
        make_float4(h0v, h1v, h2v, h3v);
    if (dq == 0) {
        *(float4*)(Pp + ((size_t)(b * NC_ + c)) * 16 + ng * 4) =
            make_float4(P0, P1, P2, P3);
    }
}

// K2b: cross-chunk combine. 8192 threads = (b, d, n); serial over 127 chunk steps.
__global__ __launch_bounds__(256, 4) void k2b_combine(float* __restrict__ ws) {
    const float* hL = ws + HL_OFF;
    const float* Pp = ws + P_OFF;
    float* h0 = ws + H0_OFF;
    const int tid = blockIdx.x * 256 + threadIdx.x;  // 0..8191
    const int b = tid >> 11;
    const int dn = tid & 2047;
    const int n = tid & 15;

    const float* hp = hL + (size_t)b * NC_ * 2048 + dn;
    const float* pp = Pp + (size_t)b * NC_ * 16 + n;
    float* op = h0 + (size_t)b * NC_ * 2048 + dn;

    float h = 0.f;
    op[0] = 0.f;
#pragma unroll 8
    for (int c = 0; c < NC_ - 1; ++c) {
        float hl = hp[(size_t)c * 2048];
        float p  = pp[(size_t)c * 16];
        h = fmaf(p, h, hl);
        op[(size_t)(c + 1) * 2048] = h;
    }
}

// K2c: rescan from h0, produce y. Same geometry as k2a; 2-stage prefetch.
__global__ __launch_bounds__(256, 4) void k2c_scan(const float* __restrict__ x,
                                                   const float* __restrict__ ws,
                                                   float* __restrict__ y) {
    const float* abar = ws + ABAR_OFF;
    const float* coef = ws + COEF_OFF;
    const float* cc   = ws + CC_OFF;
    const float* h0   = ws + H0_OFF;

    const int gw = blockIdx.x * 4 + (threadIdx.x >> 6);
    const int lane = threadIdx.x & 63;
    const int b = gw >> 10;
    const int dgrp = (gw >> 7) & 7;
    const int c = gw & 127;
    const int ng = lane >> 4;
    const int dq = lane & 15;
    const int d = dgrp * 16 + dq;
    const int l0 = c * CHUNK_;
    const float* pa = abar + ((size_t)b * L_ + l0) * 16 + ng * 4;
    const float* pc = coef + ((size_t)b * L_ + l0) * 16 + ng * 4;
    const float* pC = cc   + ((size_t)b * L_ + l0) * 16 + ng * 4;
    const float* px = x + ((size_t)b * L_ + l0) * 128 + d;
    float* py = y + ((size_t)b * L_ + l0) * 128 + d;

    float4 h4 = *(const float4*)(h0 + (((size_t)(b * NC_ + c)) * 128 + d) * 16 + ng * 4);
    float h0v = h4.x, h1v = h4.y, h2v = h4.z, h3v = h4.w;

    float4 a4 = *(const float4*)pa;
    float4 c4 = *(const float4*)pc;
    float4 C4 = *(const float4*)pC;
    float xv = px[0];
#pragma unroll 8
    for (int t = 0; t < CHUNK_; ++t) {
        float4 an, cn, Cn;
        float xn;
        if (t < CHUNK_ - 1) {
            an = *(const float4*)(pa + (t + 1) * 16);
            cn = *(const float4*)(pc + (t + 1) * 16);
            Cn = *(const float4*)(pC + (t + 1) * 16);
            xn = px[(t + 1) * 128];
        }
        h0v = fmaf(a4.x, h0v, c4.x * xv);
        h1v = fmaf(a4.y, h1v, c4.y * xv);
        h2v = fmaf(a4.z, h2v, c4.z * xv);
        h3v = fmaf(a4.w, h3v, c4.w * xv);
        float yv = h0v * C4.x + h1v * C4.y + h2v * C4.z + h3v * C4.w;
        yv += __shfl_xor(yv, 16);
        yv += __shfl_xor(yv, 32);
        if (ng == 0) py[t * 128] = yv;
        if (t < CHUNK_ - 1) { a4 = an; c4 = cn; C4 = Cn; xv = xn; }
    }
}

extern "C" void kernel_launch(void* const* d_in, const int* in_sizes, int n_in,
                              void* d_out, int out_size, void* d_ws, size_t ws_size,
                              hipStream_t stream) {
    const float* x  = (const float*)d_in[0];
    const float* A  = (const float*)d_in[1];
    const float* Wb = (const float*)d_in[2];
    const float* bb = (const float*)d_in[3];
    const float* Wc = (const float*)d_in[4];
    const float* bc = (const float*)d_in[5];
    const float* Wd = (const float*)d_in[6];
    const float* bd = (const float*)d_in[7];
    float* ws = (float*)d_ws;
    float* y  = (float*)d_out;

    k1_proj<<<512, 256, 0, stream>>>(x, A, Wb, bb, Wc, bc, Wd, bd, ws);
    k2a_chunk<<<1024, 256, 0, stream>>>(x, ws);
    k2b_combine<<<32, 256, 0, stream>>>(ws);
    k2c_scan<<<1024, 256, 0, stream>>>(x, ws, y);
}